// Round 13
// baseline (330.649 us; speedup 1.0000x reference)
//
#include <hip/hip_runtime.h>
#include <hip/hip_fp16.h>

// NCC loss: 9^3 box sums of {I, J, I*I, J*J, I*J}, per-voxel cc, -mean(cc).
// Dims: C=2, D=192, H=224, W=192, fp32.
// D-FIRST factorization:
//   P1 (k_dprod): K2-shaped stream producer (proven ~37 us). Thread owns a
//     (h,w) px-pair, marches D with a 9-deep register ring of the 5 products;
//     writes D-summed fields fp16. Zero LDS / cross-lane / barriers.
//   P2 (k_hwcc): H-march consumer. vs round 12: drop-row loads issued at the
//     TOP of each step (L3-latency cover ~500cyc under add+window+cc), HT2
//     28->16 (2.25 -> 3.9 waves/SIMD), pointer-bump addressing with +-8B
//     immediate halos, edge-only zero fill. Writes nothing but the reduce.

#define C2   2
#define DDIM 192
#define HDIM 224
#define WDIM 192
#define HWN  (HDIM*WDIM)              // 43008
#define VOL  ((size_t)DDIM*HWN)       // 8257536 (per input channel)
#define SVOL ((size_t)DDIM*HWN)       // per (f,c) field plane
#define RAD  4
#define WINV (1.0f/729.0f)

#define HT2  16   // P2 h-strip (224/16 = 14 strips)

// ---------------- P1: D-direction box sum of the 5 product fields ----------------
// grid: (HWN/512, DDIM/DS, C2); block 256; thread owns px-pair (2*pair, 2*pair+1)
// buf layout (fp16): [f][c][d][h][w]
__global__ __launch_bounds__(256)
void k_dprod(const float* __restrict__ I, const float* __restrict__ J,
             __half* __restrict__ buf, int DS)
{
    const int tid  = threadIdx.x;
    const int pair = blockIdx.x*256 + tid;    // HWN/2 = 21504 pairs
    const int pix  = 2*pair;
    const int c    = blockIdx.z;
    const int ds0  = blockIdx.y*DS;

    const float* Ib = I + (size_t)c*VOL + pix;
    const float* Jb = J + (size_t)c*VOL + pix;

    __half* ob0 = buf + (size_t)(0*C2 + c)*SVOL + pix;
    __half* ob1 = buf + (size_t)(1*C2 + c)*SVOL + pix;
    __half* ob2 = buf + (size_t)(2*C2 + c)*SVOL + pix;
    __half* ob3 = buf + (size_t)(3*C2 + c)*SVOL + pix;
    __half* ob4 = buf + (size_t)(4*C2 + c)*SVOL + pix;

    float2 ring[5][9];
    float2 rs[5];
    #pragma unroll
    for (int f = 0; f < 5; ++f) { rs[f].x = 0.f; rs[f].y = 0.f; }

    #pragma unroll
    for (int k = 0; k < 8; ++k) {
        const int dd = ds0 - RAD + k;
        float2 iv = {0.f,0.f}, jv = {0.f,0.f};
        if ((unsigned)dd < (unsigned)DDIM) {
            iv = *(const float2*)(Ib + (size_t)dd*HWN);
            jv = *(const float2*)(Jb + (size_t)dd*HWN);
        }
        float2 pr[5];
        pr[0] = iv; pr[1] = jv;
        pr[2].x = iv.x*iv.x; pr[2].y = iv.y*iv.y;
        pr[3].x = jv.x*jv.x; pr[3].y = jv.y*jv.y;
        pr[4].x = iv.x*jv.x; pr[4].y = iv.y*jv.y;
        #pragma unroll
        for (int f = 0; f < 5; ++f) {
            ring[f][k] = pr[f];
            rs[f].x += pr[f].x; rs[f].y += pr[f].y;
        }
    }

    int i = 0;
    while (i < DS) {
        #pragma unroll
        for (int p = 0; p < 9; ++p) {   // i == p (mod 9) whenever body runs
            if (i < DS) {
                const int dd = ds0 + i + RAD;    // incoming slice
                float2 iv = {0.f,0.f}, jv = {0.f,0.f};
                if (dd < DDIM) {
                    iv = *(const float2*)(Ib + (size_t)dd*HWN);
                    jv = *(const float2*)(Jb + (size_t)dd*HWN);
                }
                float2 pr[5];
                pr[0] = iv; pr[1] = jv;
                pr[2].x = iv.x*iv.x; pr[2].y = iv.y*iv.y;
                pr[3].x = jv.x*jv.x; pr[3].y = jv.y*jv.y;
                pr[4].x = iv.x*jv.x; pr[4].y = iv.y*jv.y;
                const size_t doff = (size_t)(ds0 + i)*HWN;   // output slice d
                #pragma unroll
                for (int f = 0; f < 5; ++f) {
                    rs[f].x += pr[f].x; rs[f].y += pr[f].y;
                    const __half2 h2 = __floats2half2_rn(rs[f].x, rs[f].y);
                    __half* ob = (f==0)?ob0:(f==1)?ob1:(f==2)?ob2:(f==3)?ob3:ob4;
                    *reinterpret_cast<__half2*>(ob + doff) = h2;
                    rs[f].x -= ring[f][p].x; rs[f].y -= ring[f][p].y;
                    ring[f][(p+8)%9] = pr[f];
                }
                ++i;
            }
        }
    }
}

// ---------------- P2: H-sum + W-window + cc + reduce, zero-LDS ----------------
// grid: (DDIM/4, HDIM/HT2, C2); block 192 = 48 w-groups x 4 d-slices
__global__ __launch_bounds__(192)
void k_hwcc(const __half* __restrict__ buf, double* __restrict__ gacc)
{
    const int tid  = threadIdx.x;
    const int wg   = tid % 48;        // w-group (4 px)
    const int dloc = tid / 48;
    const int w0   = 4*wg;
    const int d    = (int)blockIdx.x*4 + dloc;
    const int h0   = (int)blockIdx.y*HT2;
    const int c    = (int)blockIdx.z;
    const bool le = (wg == 0), re = (wg == 47);

    const size_t FS = (size_t)C2*SVOL;           // field stride (halves)
    const __half* base = buf + (size_t)c*SVOL + (size_t)d*HWN + w0;

    // running H-sums per field: L=[w0-4..w0-1] M=[w0..w0+3] R=[w0+4..w0+7]
    float4 L[5], M[5], R[5];
    #pragma unroll
    for (int f = 0; f < 5; ++f) {
        L[f].x=L[f].y=L[f].z=L[f].w=0.f;
        M[f].x=M[f].y=M[f].z=M[f].w=0.f;
        R[f].x=R[f].y=R[f].z=R[f].w=0.f;
    }

    uint2 pa[5][3], da[5][3];

    // span load through bumped row pointers; halos are +-8B immediate offsets
#define LOADSPAN(P, OK, A)                                                    \
    if (OK) {                                                                 \
        _Pragma("unroll")                                                     \
        for (int f = 0; f < 5; ++f) {                                         \
            A[f][1] = *reinterpret_cast<const uint2*>(P[f]);                  \
            if (!le) A[f][0] = *reinterpret_cast<const uint2*>(P[f] - 4);     \
            else     { A[f][0].x = 0u; A[f][0].y = 0u; }                      \
            if (!re) A[f][2] = *reinterpret_cast<const uint2*>(P[f] + 4);     \
            else     { A[f][2].x = 0u; A[f][2].y = 0u; }                      \
        }                                                                     \
    } else {                                                                  \
        _Pragma("unroll")                                                     \
        for (int f = 0; f < 5; ++f) {                                         \
            A[f][0].x=A[f][0].y=0u; A[f][1].x=A[f][1].y=0u;                   \
            A[f][2].x=A[f][2].y=0u;                                           \
        }                                                                     \
    }

    // S += sgn * cvt(4 halves of U) — fmaf form lets compiler use mixed fma
#define CVTACC(U, S, SGN)                                                     \
    {                                                                         \
        const __half2 h01 = __builtin_bit_cast(__half2, U.x);                 \
        const __half2 h23 = __builtin_bit_cast(__half2, U.y);                 \
        S.x = fmaf(__half2float(h01.x), SGN, S.x);                            \
        S.y = fmaf(__half2float(h01.y), SGN, S.y);                            \
        S.z = fmaf(__half2float(h23.x), SGN, S.z);                            \
        S.w = fmaf(__half2float(h23.y), SGN, S.w);                            \
    }

#define ACCROW(A, SGN)                                                        \
    _Pragma("unroll")                                                         \
    for (int f = 0; f < 5; ++f) {                                             \
        CVTACC(A[f][0], L[f], SGN);                                           \
        CVTACC(A[f][1], M[f], SGN);                                           \
        CVTACC(A[f][2], R[f], SGN);                                           \
    }

    // warm-up: rows h0-4 .. h0+3 (indexed addressing; cold anyway)
    {
        const __half* pW[5];
        #pragma unroll
        for (int f = 0; f < 5; ++f) pW[f] = base + f*FS + (size_t)(h0 - RAD)*WDIM;
        for (int k = 0; k < 8; ++k) {
            const bool ok = (h0 - RAD + k >= 0);
            LOADSPAN(pW, ok, da);
            ACCROW(da, 1.0f);
            #pragma unroll
            for (int f = 0; f < 5; ++f) pW[f] += WDIM;
        }
    }

    // bumped pointers: pA at add row (h0+4), pD at drop row (h0-4)
    const __half* pA[5];
    const __half* pD[5];
    #pragma unroll
    for (int f = 0; f < 5; ++f) {
        pA[f] = base + f*FS + (size_t)(h0 + RAD)*WDIM;
        pD[f] = base + f*FS + (size_t)(h0 - RAD)*WDIM;
    }
    // prefetch step-0 add row (h0+4 always < HDIM)
    LOADSPAN(pA, true, pa);

    float acc = 0.f;

    for (int i = 0; i < HT2; ++i) {
        const int h = h0 + i;
        // (1) issue drop-row loads FIRST (L3 latency covered by the rest)
        const bool okD = (h - RAD >= 0);
        LOADSPAN(pD, okD, da);
        #pragma unroll
        for (int f = 0; f < 5; ++f) pD[f] += WDIM;
        // (2) accumulate prefetched add row h+4
        ACCROW(pa, 1.0f);
        // (3) prefetch next add row h+5
        const bool okA = (i + 1 < HT2) && (h + RAD + 1 < HDIM);
        #pragma unroll
        for (int f = 0; f < 5; ++f) pA[f] += WDIM;
        LOADSPAN(pA, okA, pa);
        // (4) 9-tap W window + cc for 4 px
        float o[5][4];
        #pragma unroll
        for (int f = 0; f < 5; ++f) {
            const float o0 = ((L[f].x+L[f].y)+(L[f].z+L[f].w))
                           + ((M[f].x+M[f].y)+(M[f].z+M[f].w)) + R[f].x;
            o[f][0] = o0;
            o[f][1] = o0      - L[f].x + R[f].y;
            o[f][2] = o[f][1] - L[f].y + R[f].z;
            o[f][3] = o[f][2] - L[f].z + R[f].w;
        }
        #pragma unroll
        for (int j = 0; j < 4; ++j) {
            const float uI    = o[0][j]*WINV;
            const float uJ    = o[1][j]*WINV;
            const float cross = o[4][j] - uJ*o[0][j];
            const float Iv    = o[2][j] - uI*o[0][j];
            const float Jv    = o[3][j] - uJ*o[1][j];
            acc += cross*cross / (Iv*Jv + 1e-5f);
        }
        // (5) subtract drop row h-4
        ACCROW(da, -1.0f);
    }
#undef ACCROW
#undef CVTACC
#undef LOADSPAN

    // block reduction (3 waves) -> one double atomic per block
    __shared__ float wred[3];
    #pragma unroll
    for (int off = 32; off > 0; off >>= 1) acc += __shfl_down(acc, off);
    if ((tid & 63) == 0) wred[tid >> 6] = acc;
    __syncthreads();
    if (tid == 0) {
        const float sum = wred[0] + wred[1] + wred[2];
        atomicAdd(gacc, (double)sum);
    }
}

__global__ void k_fin(const double* __restrict__ gacc, float* __restrict__ out)
{
    out[0] = (float)(-gacc[0] / (double)((size_t)C2*DDIM*HDIM*WDIM));
}

extern "C" void kernel_launch(void* const* d_in, const int* in_sizes, int n_in,
                              void* d_out, int out_size, void* d_ws, size_t ws_size,
                              hipStream_t stream)
{
    if (n_in < 2) return;
    const float* I = (const float*)d_in[0];
    const float* J = (const float*)d_in[1];
    float* out = (float*)d_out;
    double* gacc = (double*)d_ws;
    __half* buf = (__half*)((char*)d_ws + 256);

    const size_t need = 256 + (size_t)5*C2*SVOL*sizeof(__half);  // 165 MB
    if (need > ws_size) return;

    hipMemsetAsync(d_ws, 0, 256, stream);   // zero the double accumulator

    const int DS = 48;
    dim3 g1(HWN/512, DDIM/DS, C2);           // 84 x 4 x 2 blocks
    k_dprod<<<g1, dim3(256,1,1), 0, stream>>>(I, J, buf, DS);

    dim3 g2(DDIM/4, HDIM/HT2, C2);           // 48 x 14 x 2 blocks
    k_hwcc<<<g2, dim3(192,1,1), 0, stream>>>(buf, gacc);

    k_fin<<<1,1,0,stream>>>(gacc, out);
}

// Round 14
// 164.953 us; speedup vs baseline: 2.0045x; 2.0045x over previous
//
#include <hip/hip_runtime.h>
#include <hip/hip_fp16.h>

// NCC loss: 9^3 box sums of {I, J, I*I, J*J, I*J}, per-voxel cc, -mean(cc).
// Dims: C=2, D=192, H=224, W=192, fp32.
// Empirical law from rounds 1-13: kernels that MARCH THE OUTERMOST AXIS run
// at 5.9-8 TB/s; kernels that march the middle axis (H) pin at 0.6-3 TB/s,
// regardless of LDS/shuffles/stores/occupancy. So: transpose the intermediate.
//   P1 (k_dwprod): march-D producer + in-thread W-sum. Thread owns 2 px,
//     loads its 10-px span (5 aligned float2 of I,J; overlap via L1),
//     W-rolls, rounds W-sum to half2, half2-ring[5][9] along D (exact
//     add/drop cancellation of the rounded value), stores W+D-sums to
//     TRANSPOSED layout [f][c][h][d][w].
//   P2 (k_hcc): proven K2 structure marching H = outermost axis of the
//     transposed buffer. 5 loads/step, fp32 ring[5][9], cc, block reduce.

#define C2   2
#define DDIM 192
#define HDIM 224
#define WDIM 192
#define HWN  (HDIM*WDIM)              // 43008
#define VOL  ((size_t)DDIM*HWN)       // 8257536 per input channel
#define PLN  (DDIM*WDIM)              // 36864 = transposed inner (d,w) plane
#define RAD  4
#define WINV (1.0f/729.0f)

#define DS1  48   // P1 D-sub-chunk (192/48 = 4)
#define HS2  56   // P2 H-sub-chunk (224/56 = 4)

// ---------------- P1: W-sum (in-thread) + D-sum (half2 ring), march D ----------------
// grid: (HDIM/2, DDIM/DS1, C2); block 192 = 2 h-rows x 96 threads (2 px each)
// out layout (fp16): [f][c][h][d][w]
__global__ __launch_bounds__(192)
void k_dwprod(const float* __restrict__ I, const float* __restrict__ J,
              __half* __restrict__ buf, int d0)
{
    const int tid = threadIdx.x;
    const int li  = tid % 96;          // lane-in-row
    const int r   = tid / 96;          // row within block (0/1)
    const int w0  = 2*li;
    const int h   = 2*(int)blockIdx.x + r;
    const int c   = (int)blockIdx.z;
    const int ds0 = d0 + (int)blockIdx.y*DS1;

    const bool mA = (li >= 2), mB = (li >= 1), mD = (li <= 94), mE = (li <= 93);

    const float* Ib = I + (size_t)c*VOL + (size_t)h*WDIM + w0;
    const float* Jb = J + (size_t)c*VOL + (size_t)h*WDIM + w0;

    // transposed output bases: field f plane at ((f*C2+c)*HDIM + h)*PLN + w0
    __half* ob[5];
    #pragma unroll
    for (int f = 0; f < 5; ++f)
        ob[f] = buf + ((size_t)(f*C2 + c)*HDIM + h)*PLN + w0;

    __half2 ring[5][9];
    float2  rs[5];
    #pragma unroll
    for (int f = 0; f < 5; ++f) { rs[f].x = 0.f; rs[f].y = 0.f; }

    // per-slice W-sum -> rounded half2 (o0 at w0, o1 at w0+1)
#define WSLICE(DD, DOK, OUT)                                                  \
    {                                                                         \
        float iv[10], jv[10];                                                 \
        _Pragma("unroll") for (int t = 0; t < 10; ++t) { iv[t]=0.f; jv[t]=0.f; } \
        if (DOK) {                                                            \
            const float* ri = Ib + (size_t)(DD)*HWN;                          \
            const float* rj = Jb + (size_t)(DD)*HWN;                          \
            float2 v;                                                         \
            v = *(const float2*)(ri);     iv[4]=v.x; iv[5]=v.y;               \
            v = *(const float2*)(rj);     jv[4]=v.x; jv[5]=v.y;               \
            if (mA) { v = *(const float2*)(ri-4); iv[0]=v.x; iv[1]=v.y;       \
                      v = *(const float2*)(rj-4); jv[0]=v.x; jv[1]=v.y; }     \
            if (mB) { v = *(const float2*)(ri-2); iv[2]=v.x; iv[3]=v.y;       \
                      v = *(const float2*)(rj-2); jv[2]=v.x; jv[3]=v.y; }     \
            if (mD) { v = *(const float2*)(ri+2); iv[6]=v.x; iv[7]=v.y;       \
                      v = *(const float2*)(rj+2); jv[6]=v.x; jv[7]=v.y; }     \
            if (mE) { v = *(const float2*)(ri+4); iv[8]=v.x; iv[9]=v.y;       \
                      v = *(const float2*)(rj+4); jv[8]=v.x; jv[9]=v.y; }     \
        }                                                                     \
        float s8;                                                             \
        s8 = 0.f; _Pragma("unroll") for (int t=1;t<9;++t) s8 += iv[t];        \
        OUT[0] = __floats2half2_rn(s8+iv[0], s8+iv[9]);                       \
        s8 = 0.f; _Pragma("unroll") for (int t=1;t<9;++t) s8 += jv[t];        \
        OUT[1] = __floats2half2_rn(s8+jv[0], s8+jv[9]);                       \
        s8 = 0.f; _Pragma("unroll") for (int t=1;t<9;++t) s8 += iv[t]*iv[t];  \
        OUT[2] = __floats2half2_rn(s8+iv[0]*iv[0], s8+iv[9]*iv[9]);           \
        s8 = 0.f; _Pragma("unroll") for (int t=1;t<9;++t) s8 += jv[t]*jv[t];  \
        OUT[3] = __floats2half2_rn(s8+jv[0]*jv[0], s8+jv[9]*jv[9]);           \
        s8 = 0.f; _Pragma("unroll") for (int t=1;t<9;++t) s8 += iv[t]*jv[t];  \
        OUT[4] = __floats2half2_rn(s8+iv[0]*jv[0], s8+iv[9]*jv[9]);           \
    }

    // warm-up: slices ds0-4 .. ds0+3
    #pragma unroll
    for (int k = 0; k < 8; ++k) {
        const int dd = ds0 - RAD + k;
        __half2 wsl[5];
        WSLICE(dd, (dd >= 0), wsl);
        #pragma unroll
        for (int f = 0; f < 5; ++f) {
            ring[f][k] = wsl[f];
            const float2 wr = __half22float2(wsl[f]);
            rs[f].x += wr.x; rs[f].y += wr.y;
        }
    }

    int i = 0;
    while (i < DS1) {
        #pragma unroll
        for (int p = 0; p < 9; ++p) {   // i == p (mod 9) whenever body runs
            if (i < DS1) {
                const int dd = ds0 + i + RAD;    // incoming slice
                __half2 wsl[5];
                WSLICE(dd, (dd < DDIM), wsl);
                const size_t doff = (size_t)(ds0 + i)*WDIM;  // output slice d
                #pragma unroll
                for (int f = 0; f < 5; ++f) {
                    const float2 wa = __half22float2(wsl[f]);
                    rs[f].x += wa.x; rs[f].y += wa.y;        // window [d-4..d+4]
                    *reinterpret_cast<__half2*>(ob[f] + doff)
                        = __floats2half2_rn(rs[f].x, rs[f].y);
                    const float2 wd = __half22float2(ring[f][p]);
                    rs[f].x -= wd.x; rs[f].y -= wd.y;        // drop d-4 (exact)
                    ring[f][(p+8)%9] = wsl[f];               // keep d+4
                }
                ++i;
            }
        }
    }
#undef WSLICE
}

// -------- P2: H-sum (register ring) + cc + block reduce — march outermost H --------
// grid: (PLN/256, HDIM/HS2, C2); block 256
__global__ __launch_bounds__(256)
void k_hcc(const __half* __restrict__ buf, double* __restrict__ gacc)
{
    const int tid = threadIdx.x;
    const int pix = blockIdx.x*256 + tid;      // (d,w) flat, PLN = 144*256 exact
    const int c   = blockIdx.z;
    const int hs0 = blockIdx.y*HS2;

    const size_t fstride = (size_t)C2*HDIM*PLN;
    const __half* base = buf + (size_t)c*HDIM*PLN + pix;

    float ring[5][9];
    float rs[5] = {0.f,0.f,0.f,0.f,0.f};
    float acc = 0.f;

    // warm-up: rows hs0-4 .. hs0+3
    #pragma unroll
    for (int k = 0; k < 8; ++k) {
        const int hh = hs0 - RAD + k;
        float v[5] = {0.f,0.f,0.f,0.f,0.f};
        if (hh >= 0) {
            const __half* pp = base + (size_t)hh*PLN;
            #pragma unroll
            for (int f = 0; f < 5; ++f) v[f] = __half2float(pp[(size_t)f*fstride]);
        }
        #pragma unroll
        for (int f = 0; f < 5; ++f) { ring[f][k] = v[f]; rs[f] += v[f]; }
    }

    int i = 0;
    while (i < HS2) {
        #pragma unroll
        for (int p = 0; p < 9; ++p) {   // i == p (mod 9) whenever body runs
            if (i < HS2) {
                const int hh = hs0 + i + RAD;
                float v[5] = {0.f,0.f,0.f,0.f,0.f};
                if (hh < HDIM) {
                    const __half* pp = base + (size_t)hh*PLN;
                    #pragma unroll
                    for (int f = 0; f < 5; ++f) v[f] = __half2float(pp[(size_t)f*fstride]);
                }
                float S[5];
                #pragma unroll
                for (int f = 0; f < 5; ++f) {
                    rs[f] += v[f];              // full 9x9x9 sum at row hs0+i
                    S[f] = rs[f];
                    rs[f] -= ring[f][p];        // drop row -8
                    ring[f][(p+8)%9] = v[f];    // keep row +4
                }
                const float uI    = S[0]*WINV;
                const float uJ    = S[1]*WINV;
                const float cross = S[4] - uJ*S[0];
                const float Iv    = S[2] - uI*S[0];
                const float Jv    = S[3] - uJ*S[1];
                acc += cross*cross / (Iv*Jv + 1e-5f);
                ++i;
            }
        }
    }

    // block reduction -> one double atomic per block
    __shared__ float wred[4];
    #pragma unroll
    for (int off = 32; off > 0; off >>= 1) acc += __shfl_down(acc, off);
    if ((tid & 63) == 0) wred[tid >> 6] = acc;
    __syncthreads();
    if (tid == 0) {
        const float sum = wred[0] + wred[1] + wred[2] + wred[3];
        atomicAdd(gacc, (double)sum);
    }
}

__global__ void k_fin(const double* __restrict__ gacc, float* __restrict__ out)
{
    out[0] = (float)(-gacc[0] / (double)((size_t)C2*DDIM*HDIM*WDIM));
}

extern "C" void kernel_launch(void* const* d_in, const int* in_sizes, int n_in,
                              void* d_out, int out_size, void* d_ws, size_t ws_size,
                              hipStream_t stream)
{
    if (n_in < 2) return;
    const float* I = (const float*)d_in[0];
    const float* J = (const float*)d_in[1];
    float* out = (float*)d_out;
    double* gacc = (double*)d_ws;
    __half* buf = (__half*)((char*)d_ws + 256);

    // transposed fp16 DW-summed fields: 5*2*224*36864*2 B = 165 MB
    const size_t need = 256 + (size_t)5*C2*HDIM*PLN*sizeof(__half);
    if (need > ws_size) return;

    hipMemsetAsync(d_ws, 0, 256, stream);   // zero the double accumulator

    dim3 g1(HDIM/2, DDIM/DS1, C2);           // 112 x 4 x 2 blocks
    k_dwprod<<<g1, dim3(192,1,1), 0, stream>>>(I, J, buf, 0);

    dim3 g2(PLN/256, HDIM/HS2, C2);          // 144 x 4 x 2 blocks
    k_hcc<<<g2, dim3(256,1,1), 0, stream>>>(buf, gacc);

    k_fin<<<1,1,0,stream>>>(gacc, out);
}